// Round 10
// baseline (278.451 us; speedup 1.0000x reference)
//
#include <hip/hip_runtime.h>

// ---------------------------------------------------------------------------
// CorefPairScorer: B=4, T=4096, D=768, N=256, HID=200 (padded to 224)
// h1(i,j) = relu(A[i] + Bv[j] + (emb_i*emb_j)@W1bot + b1)
// h2 = relu(h1@W2 + b2); s = h2@W3 + b3; masked softmax rows.
// R15: 4 rows/wave, 2 waves/SIMD: 110us, MfmaUtil 23%. Issue economics:
//   136 cyc MFMA vs ~100 cyc VALU+loads per step at 2 waves -> ~25% ceiling.
// R16 "fat wave": 8 i-rows/wave, acc[8][7]=224 AGPR. 56 MFMA (272 cyc matrix)
//   per 16 loads per step -> single wave covers L2 latency by itself.
//   ~390/512 unified regs -> 1 wave/SIMD, 2-wave blocks, 2 blocks/CU
//   (LDS 58.4KB). Spill guards: acc scope dies before acc2; named ping-pong
//   buffers; unroll 1; launch_bounds(128,1) (no cap).
// ---------------------------------------------------------------------------

#define NB 4
#define NN 256
#define DD 768
#define TT 4096
#define HP 224
#define NTILES 14
#define KT1 24
#define KT2 7
#define TRI 136
#define ABS 448          // AB row stride (fp16): [A(224) | B(224)]
#define MTS 3584         // shorts per packed Mtile (16 rows x 224)

typedef _Float16 f16x8 __attribute__((ext_vector_type(8)));
typedef _Float16 f16x2 __attribute__((ext_vector_type(2)));
typedef __attribute__((ext_vector_type(4))) float f32x4;

union FragU { uint4 u; f16x8 h; };
union H2U { unsigned int u; f16x2 h; };

__device__ __forceinline__ unsigned int h2mul(unsigned int a, unsigned int b) {
    H2U x, y, r; x.u = a; y.u = b; r.h = x.h * y.h;   // v_pk_mul_f16
    return r.u;
}
__device__ __forceinline__ float hlo(unsigned int v) { H2U x; x.u = v; return (float)x.h[0]; }
__device__ __forceinline__ float hhi(unsigned int v) { H2U x; x.u = v; return (float)x.h[1]; }
__device__ __forceinline__ unsigned short f2h(float f) {
    _Float16 h = (_Float16)f;
    union { _Float16 h; unsigned short u; } r; r.h = h; return r.u;
}
__device__ __forceinline__ float h2f(unsigned short u) {
    union { unsigned short u; _Float16 h; } r; r.u = u; return (float)r.h;
}

// ---------------------------------------------------------------------------
// K0 (merged): weight swizzle (blocks 0..2211) + gather/cast (blocks 2212..3235)
//   frag layout: buf[((kt*NT+nt)*64+lane)*8+j] = W[kt*32+(lane>>4)*8+j][nt*16+(lane&15)]
// ---------------------------------------------------------------------------
__global__ void prep_all(const float* __restrict__ W1, const float* __restrict__ W2,
                         const float* __restrict__ ee, const int* __restrict__ eidx,
                         unsigned short* __restrict__ w1n,
                         unsigned short* __restrict__ w1s,
                         unsigned short* __restrict__ w2s,
                         unsigned short* __restrict__ emb) {
    const int N1n = 24 * 28 * 512;   // 344064
    const int N1s = 24 * 14 * 512;   // 172032
    const int N2  = 7 * 14 * 512;    // 50176
    int bx = blockIdx.x;
    if (bx >= 2212) {                 // gather + fp32->fp16
        int g = bx - 2212;
        int b = g >> 8, n = g & 255;
        int t = eidx[b * NN + n];
        const float* src = ee + ((size_t)b * TT + t) * DD;
        unsigned short* dst = emb + ((size_t)b * NN + n) * DD;
        for (int e = threadIdx.x; e < DD; e += 256) dst[e] = f2h(src[e]);
        return;
    }
    int idx = bx * 256 + threadIdx.x;
    if (idx < N1n) {
        int j = idx & 7, lane = (idx >> 3) & 63, f = idx >> 9;
        int nt = f % 28, kt = f / 28;
        int k = kt * 32 + (lane >> 4) * 8 + j;     // 0..767
        int n = nt * 16 + (lane & 15);             // 0..447
        float v;
        if (n < HP) v = (n < 200) ? W1[(size_t)k * 200 + n] : 0.f;
        else { int c2 = n - HP; v = (c2 < 200) ? W1[(size_t)(768 + k) * 200 + c2] : 0.f; }
        w1n[idx] = f2h(v);
    } else if (idx < N1n + N1s) {
        int i2 = idx - N1n;
        int j = i2 & 7, lane = (i2 >> 3) & 63, f = i2 >> 9;
        int nt = f % NTILES, kt = f / NTILES;
        int k = kt * 32 + (lane >> 4) * 8 + j;
        int n = nt * 16 + (lane & 15);
        float v = (n < 200) ? W1[(size_t)(1536 + k) * 200 + n] : 0.f;
        w1s[i2] = f2h(v);
    } else if (idx < N1n + N1s + N2) {
        int i2 = idx - N1n - N1s;
        int j = i2 & 7, lane = (i2 >> 3) & 63, f = i2 >> 9;
        int nt = f % NTILES, kt = f / NTILES;
        int k = kt * 32 + (lane >> 4) * 8 + j;
        int n = nt * 16 + (lane & 15);
        float v = (k < 200 && n < 200) ? W2[(size_t)k * 200 + n] : 0.f;
        w2s[i2] = f2h(v);
    }
}

// ---------------------------------------------------------------------------
// K2: AB = emb(1024x768) @ [W1top|W1mid](768x448), fp16 MFMA, fp16 out.
//   256 one-wave blocks; register ping-pong prefetch.
// ---------------------------------------------------------------------------
__global__ __launch_bounds__(64)
void node_mfma(const unsigned short* __restrict__ emb,
               const unsigned short* __restrict__ w1n,
               unsigned short* __restrict__ AB) {
    int lane = threadIdx.x & 63;
    int q = lane >> 4, c = lane & 15;
    int mt = blockIdx.x >> 2;         // 0..63
    int ng = blockIdx.x & 3;          // 0..3
    int m0 = mt * 16;
    const uint4* ga = (const uint4*)emb + (size_t)(m0 + c) * 96;
    const uint4* gb = (const uint4*)w1n;

    f32x4 acc[7];
#pragma unroll
    for (int n = 0; n < 7; ++n) acc[n] = (f32x4){0.f, 0.f, 0.f, 0.f};

    uint4 aA, aB, bA[7], bB[7];
    aA = ga[q];
#pragma unroll
    for (int n = 0; n < 7; ++n) bA[n] = gb[((0 * 28 + ng * 7 + n) << 6) + lane];

#pragma unroll 1
    for (int kt = 0; kt < KT1; kt += 2) {
        aB = ga[(kt + 1) * 4 + q];
#pragma unroll
        for (int n = 0; n < 7; ++n) bB[n] = gb[(((kt + 1) * 28 + ng * 7 + n) << 6) + lane];
        {
            FragU a; a.u = aA;
#pragma unroll
            for (int n = 0; n < 7; ++n) {
                FragU bb; bb.u = bA[n];
                acc[n] = __builtin_amdgcn_mfma_f32_16x16x32_f16(a.h, bb.h, acc[n], 0, 0, 0);
            }
        }
        if (kt + 2 < KT1) {
            aA = ga[(kt + 2) * 4 + q];
#pragma unroll
            for (int n = 0; n < 7; ++n) bA[n] = gb[(((kt + 2) * 28 + ng * 7 + n) << 6) + lane];
        }
        {
            FragU a; a.u = aB;
#pragma unroll
            for (int n = 0; n < 7; ++n) {
                FragU bb; bb.u = bB[n];
                acc[n] = __builtin_amdgcn_mfma_f32_16x16x32_f16(a.h, bb.h, acc[n], 0, 0, 0);
            }
        }
    }
#pragma unroll
    for (int n = 0; n < 7; ++n) {
        int col = (ng * 7 + n) * 16 + c;
#pragma unroll
        for (int rr = 0; rr < 4; ++rr)
            AB[(size_t)(m0 + q * 4 + rr) * ABS + col] = f2h(acc[n][rr]);
    }
}

// ---------------------------------------------------------------------------
// K3: pair MLP, fat-wave. Block = 128 threads = 2 waves (the nh pair) for
//   one (tile, 8-i-row half rp). Wave nh: rows iA..iA+7, ntile-half nh,
//   acc[8][7] (56 MFMA per 7 weight loads; 272 cyc matrix work per step
//   covers L2 latency within the wave). Ping-pong prefetch.
//   Phase1 -> epilogue -> smH(8 slots) -> B1 -> phase2 acc2[8][7] -> phase3
//   -> B2 -> store 128 pairs. Grid 1088 = 2 x 544.
// ---------------------------------------------------------------------------
__global__ __launch_bounds__(128, 1)
void pair_wave(
    const unsigned short* __restrict__ emb,
    const unsigned short* __restrict__ w1s,
    const unsigned short* __restrict__ w2s,
    const unsigned short* __restrict__ AB,
    const float* __restrict__ b1, const float* __restrict__ b2,
    const float* __restrict__ W3, const float* __restrict__ b3,
    float* __restrict__ S) {
    int bid = blockIdx.x;
    int rp = bid / 544;               // 0..1 : 8-row half within tile
    int g = bid % 544;                // tile id; mates 544 apart (544%8==0)
    int b = g / TRI;
    int r = g % TRI;
    int ti = (int)((sqrtf(8.f * (float)r + 1.f) - 1.f) * 0.5f);
    while ((ti + 1) * (ti + 2) / 2 <= r) ++ti;
    while (ti * (ti + 1) / 2 > r) --ti;
    int tj = r - ti * (ti + 1) / 2;
    int i0 = ti << 4, j0 = tj << 4;

    int tid = threadIdx.x;
    int lane = tid & 63;
    int nh = tid >> 6;                // 0..1 (ntile half)
    int q = lane >> 4, c = lane & 15;
    int iA = i0 + rp * 8;             // rows iA..iA+7

    __shared__ __align__(16) unsigned short smH[8 * MTS];   // 57344 B (8 slots)
    __shared__ float sred[2][128];                          //  1024 B

    const uint4* w1f = (const uint4*)w1s;
    const uint4* w2f = (const uint4*)w2s;
    const uint4* gI[8];
#pragma unroll
    for (int t = 0; t < 8; ++t)
        gI[t] = (const uint4*)(emb + ((size_t)b * NN + iA + t) * DD);
    const uint4* gJc = (const uint4*)(emb + ((size_t)b * NN + j0 + c) * DD);

    {   // ---- phase 1: acc[8][7] over K=768, ping-pong prefetch ----
        f32x4 acc[8][7];
#pragma unroll
        for (int t = 0; t < 8; ++t)
#pragma unroll
            for (int n = 0; n < 7; ++n)
                acc[t][n] = (f32x4){0.f, 0.f, 0.f, 0.f};

        {
            uint4 bfrA[7], bfrB[7];
            uint4 ejA, ejB, eA[8], eB[8];
#pragma unroll
            for (int n = 0; n < 7; ++n) bfrA[n] = w1f[(nh * 7 + n) * 64 + lane];
            ejA = gJc[q];
#pragma unroll
            for (int t = 0; t < 8; ++t) eA[t] = gI[t][q];

#pragma unroll 1
            for (int kt = 0; kt < KT1; kt += 2) {
                // prefetch kt+1 -> B
#pragma unroll
                for (int n = 0; n < 7; ++n)
                    bfrB[n] = w1f[((kt + 1) * NTILES + nh * 7 + n) * 64 + lane];
                ejB = gJc[(kt + 1) * 4 + q];
#pragma unroll
                for (int t = 0; t < 8; ++t) eB[t] = gI[t][(kt + 1) * 4 + q];
                // compute kt (A)
#pragma unroll
                for (int t = 0; t < 8; ++t) {
                    FragU a;
                    a.u.x = h2mul(eA[t].x, ejA.x); a.u.y = h2mul(eA[t].y, ejA.y);
                    a.u.z = h2mul(eA[t].z, ejA.z); a.u.w = h2mul(eA[t].w, ejA.w);
#pragma unroll
                    for (int n = 0; n < 7; ++n) {
                        FragU bb; bb.u = bfrA[n];
                        acc[t][n] = __builtin_amdgcn_mfma_f32_16x16x32_f16(a.h, bb.h, acc[t][n], 0, 0, 0);
                    }
                }
                // prefetch kt+2 -> A
                if (kt + 2 < KT1) {
#pragma unroll
                    for (int n = 0; n < 7; ++n)
                        bfrA[n] = w1f[((kt + 2) * NTILES + nh * 7 + n) * 64 + lane];
                    ejA = gJc[(kt + 2) * 4 + q];
#pragma unroll
                    for (int t = 0; t < 8; ++t) eA[t] = gI[t][(kt + 2) * 4 + q];
                }
                // compute kt+1 (B)
#pragma unroll
                for (int t = 0; t < 8; ++t) {
                    FragU a;
                    a.u.x = h2mul(eB[t].x, ejB.x); a.u.y = h2mul(eB[t].y, ejB.y);
                    a.u.z = h2mul(eB[t].z, ejB.z); a.u.w = h2mul(eB[t].w, ejB.w);
#pragma unroll
                    for (int n = 0; n < 7; ++n) {
                        FragU bb; bb.u = bfrB[n];
                        acc[t][n] = __builtin_amdgcn_mfma_f32_16x16x32_f16(a.h, bb.h, acc[t][n], 0, 0, 0);
                    }
                }
            }
        }

        // ---- epilogue: h1 = relu(acc + A[i] + Bv[j] + b1) -> smH (nh half) ----
        // acc fully consumed here, inside this scope (dies before acc2 lives).
        unsigned int bvp[7][2];
#pragma unroll
        for (int n = 0; n < 7; ++n) {
            int h = ((nh * 7 + n) << 4) + c;
#pragma unroll
            for (int p = 0; p < 2; ++p) {
                unsigned int lo = AB[((size_t)b * NN + j0 + q * 4 + 2 * p) * ABS + HP + h];
                unsigned int hi = AB[((size_t)b * NN + j0 + q * 4 + 2 * p + 1) * ABS + HP + h];
                bvp[n][p] = (hi << 16) | lo;
            }
        }
#pragma unroll
        for (int t = 0; t < 8; ++t) {
            unsigned short* slot = &smH[t * MTS];
#pragma unroll
            for (int n = 0; n < 7; ++n) {
                int h = ((nh * 7 + n) << 4) + c;
                float b1v = (h < 200) ? b1[h] : 0.f;
                float af = h2f(AB[((size_t)b * NN + iA + t) * ABS + h]) + b1v;
                int kk2 = h >> 5, q2 = (h >> 3) & 3, j2 = h & 7;
                int fa = ((kk2 * 4 + q2) << 7) + j2;        // + jj*8 below
#pragma unroll
                for (int rr = 0; rr < 4; ++rr) {
                    float bvf = (rr & 1) ? hhi(bvp[n][rr >> 1]) : hlo(bvp[n][rr >> 1]);
                    slot[fa + ((q * 4 + rr) << 3)] =
                        f2h(fmaxf(acc[t][n][rr] + af + bvf, 0.f));
                }
            }
        }
    }
    __syncthreads();   // B1: both h-halves of all 8 slots in smH

    // ---- phase 2: acc2[8][7] over K=224, ping-pong weight prefetch ----
    f32x4 acc2[8][7];
#pragma unroll
    for (int t = 0; t < 8; ++t)
#pragma unroll
        for (int n = 0; n < 7; ++n)
            acc2[t][n] = (f32x4){0.f, 0.f, 0.f, 0.f};

    {
        uint4 bfrA[7], bfrB[7];
#pragma unroll
        for (int n = 0; n < 7; ++n) bfrA[n] = w2f[(nh * 7 + n) * 64 + lane];

#pragma unroll 1
        for (int kk = 0; kk < 6; kk += 2) {
#pragma unroll
            for (int n = 0; n < 7; ++n)
                bfrB[n] = w2f[((kk + 1) * NTILES + nh * 7 + n) * 64 + lane];
#pragma unroll
            for (int t = 0; t < 8; ++t) {
                FragU a2;
                a2.u = *(const uint4*)(&smH[t * MTS + (((kk * 4 + q) * 16 + c) << 3)]);
#pragma unroll
                for (int n = 0; n < 7; ++n) {
                    FragU bb; bb.u = bfrA[n];
                    acc2[t][n] = __builtin_amdgcn_mfma_f32_16x16x32_f16(a2.h, bb.h, acc2[t][n], 0, 0, 0);
                }
            }
#pragma unroll
            for (int n = 0; n < 7; ++n)
                bfrA[n] = w2f[((kk + 2) * NTILES + nh * 7 + n) * 64 + lane];
#pragma unroll
            for (int t = 0; t < 8; ++t) {
                FragU a2;
                a2.u = *(const uint4*)(&smH[t * MTS + ((((kk + 1) * 4 + q) * 16 + c) << 3)]);
#pragma unroll
                for (int n = 0; n < 7; ++n) {
                    FragU bb; bb.u = bfrB[n];
                    acc2[t][n] = __builtin_amdgcn_mfma_f32_16x16x32_f16(a2.h, bb.h, acc2[t][n], 0, 0, 0);
                }
            }
        }
        // tail kk=6 (already in bfrA)
#pragma unroll
        for (int t = 0; t < 8; ++t) {
            FragU a2;
            a2.u = *(const uint4*)(&smH[t * MTS + (((6 * 4 + q) * 16 + c) << 3)]);
#pragma unroll
            for (int n = 0; n < 7; ++n) {
                FragU bb; bb.u = bfrA[n];
                acc2[t][n] = __builtin_amdgcn_mfma_f32_16x16x32_f16(a2.h, bb.h, acc2[t][n], 0, 0, 0);
            }
        }
    }

    // ---- phase 3: partial dot relu(h2+b2).W3 over nh half -> sred ----
    {
        float b2v[7], w3v[7];
#pragma unroll
        for (int n = 0; n < 7; ++n) {
            int h = ((nh * 7 + n) << 4) + c;
            b2v[n] = (h < 200) ? b2[h] : 0.f;
            w3v[n] = (h < 200) ? W3[h] : 0.f;
        }
#pragma unroll
        for (int t = 0; t < 8; ++t) {
#pragma unroll
            for (int rr = 0; rr < 4; ++rr) {
                float part = 0.f;
#pragma unroll
                for (int n = 0; n < 7; ++n) {
                    float hv = fmaxf(acc2[t][n][rr] + b2v[n], 0.f);
                    part += hv * w3v[n];
                }
                part += __shfl_xor(part, 1);
                part += __shfl_xor(part, 2);
                part += __shfl_xor(part, 4);
                part += __shfl_xor(part, 8);
                if (c == 0)
                    sred[nh][t * 16 + q * 4 + rr] = part;
            }
        }
    }
    __syncthreads();   // B2: both partials in sred

    {
        int t = tid >> 4, jj = tid & 15;
        float s = sred[0][tid] + sred[1][tid] + b3[0];
        S[((size_t)b * NN + iA + t) * NN + j0 + jj] = s;
    }
}

// ---------------------------------------------------------------------------
// K4: masked softmax per row; diag logit = 0; invalid -> -1000
// ---------------------------------------------------------------------------
__global__ __launch_bounds__(256) void softmax_rows(const float* __restrict__ S,
                                                    float* __restrict__ out) {
    int b = blockIdx.x >> 8, i = blockIdx.x & 255;
    int j = threadIdx.x;
    int lane = j & 63, w = j >> 6;
    __shared__ float red[16];
    float x = (j < i) ? S[((size_t)b * NN + i) * NN + j] : ((j == i) ? 0.f : -1e30f);
    float m = x;
#pragma unroll
    for (int off = 32; off; off >>= 1) m = fmaxf(m, __shfl_xor(m, off));
    if (lane == 0) red[w] = m;
    __syncthreads();
    float mx = fmaxf(fmaxf(red[0], red[1]), fmaxf(red[2], red[3]));
    float e = (j <= i) ? __expf(x - mx) : 0.f;
    float s = e;
#pragma unroll
    for (int off = 32; off; off >>= 1) s += __shfl_xor(s, off);
    if (lane == 0) red[8 + w] = s;
    __syncthreads();
    float sum = red[8] + red[9] + red[10] + red[11];
    out[((size_t)b * NN + i) * NN + j] = (j <= i) ? (e / sum) : -1000.0f;
}

// ---------------------------------------------------------------------------
extern "C" void kernel_launch(void* const* d_in, const int* in_sizes, int n_in,
                              void* d_out, int out_size, void* d_ws, size_t ws_size,
                              hipStream_t stream) {
    const float* ee  = (const float*)d_in[0];
    const int*   eidx = (const int*)d_in[1];
    const float* W1  = (const float*)d_in[2];
    const float* b1  = (const float*)d_in[3];
    const float* W2  = (const float*)d_in[4];
    const float* b2  = (const float*)d_in[5];
    const float* W3  = (const float*)d_in[6];
    const float* b3  = (const float*)d_in[7];
    float* out = (float*)d_out;

    char* p = (char*)d_ws;
    unsigned short* emb = (unsigned short*)p; p += (size_t)NB * NN * DD * 2;       // 1.5 MB
    unsigned short* w1n = (unsigned short*)p; p += (size_t)24 * 28 * 512 * 2;      // 672 KB
    unsigned short* w1s = (unsigned short*)p; p += (size_t)24 * 14 * 512 * 2;      // 336 KB
    unsigned short* w2s = (unsigned short*)p; p += (size_t)7 * 14 * 512 * 2;       // 98 KB
    unsigned short* AB  = (unsigned short*)p; p += (size_t)NB * NN * ABS * 2;      // 896 KB
    float* S  = (float*)p; p += (size_t)NB * NN * NN * 4;                           // 1 MB

    prep_all<<<3236, 256, 0, stream>>>(W1, W2, ee, eidx, w1n, w1s, w2s, emb);
    node_mfma<<<256, 64, 0, stream>>>(emb, w1n, AB);
    pair_wave<<<1088, 128, 0, stream>>>(emb, w1s, w2s, AB, b1, b2, W3, b3, S);
    softmax_rows<<<NB * NN, 256, 0, stream>>>(S, out);
}

// Round 11
// 203.346 us; speedup vs baseline: 1.3693x; 1.3693x over previous
//
#include <hip/hip_runtime.h>

// ---------------------------------------------------------------------------
// CorefPairScorer: B=4, T=4096, D=768, N=256, HID=200 (padded to 224)
// h1(i,j) = relu(A[i] + Bv[j] + (emb_i*emb_j)@W1bot + b1)
// h2 = relu(h1@W2 + b2); s = h2@W3 + b3; masked softmax rows.
// Density-vs-occupancy curve (rows/wave @ waves/SIMD -> pair_wave us):
//   2 @ 3 = 119 (R14) | 4 @ 2 = 110 (R15, optimum) | 8 @ <1 = 178+spill (R16)
// R17: revert to R15 geometry; add (a) s_setprio(1) around MFMA bursts
//   (independent out-of-phase waves = m191 regime, +4-7%); (b) vectorized
//   prep_all: 8 elems/thread uint4 stores for weight swizzle (277 blocks vs
//   2212), 4-row gather blocks with packed f16x2 stores. Non-pair time was
//   a constant ~100us across all rounds - start trimming it.
// ---------------------------------------------------------------------------

#define NB 4
#define NN 256
#define DD 768
#define TT 4096
#define HP 224
#define NTILES 14
#define KT1 24
#define KT2 7
#define TRI 136
#define ABS 448          // AB row stride (fp16): [A(224) | B(224)]
#define MTS 3584         // shorts per packed Mtile (16 rows x 224)

typedef _Float16 f16x8 __attribute__((ext_vector_type(8)));
typedef _Float16 f16x2 __attribute__((ext_vector_type(2)));
typedef __attribute__((ext_vector_type(4))) float f32x4;

union FragU { uint4 u; f16x8 h; };
union H2U { unsigned int u; f16x2 h; };

__device__ __forceinline__ unsigned int h2mul(unsigned int a, unsigned int b) {
    H2U x, y, r; x.u = a; y.u = b; r.h = x.h * y.h;   // v_pk_mul_f16
    return r.u;
}
__device__ __forceinline__ float hlo(unsigned int v) { H2U x; x.u = v; return (float)x.h[0]; }
__device__ __forceinline__ float hhi(unsigned int v) { H2U x; x.u = v; return (float)x.h[1]; }
__device__ __forceinline__ unsigned short f2h(float f) {
    _Float16 h = (_Float16)f;
    union { _Float16 h; unsigned short u; } r; r.h = h; return r.u;
}
__device__ __forceinline__ float h2f(unsigned short u) {
    union { unsigned short u; _Float16 h; } r; r.u = u; return (float)r.h;
}
__device__ __forceinline__ unsigned int packh(float lo, float hi) {  // RNE pair
    return ((unsigned int)f2h(hi) << 16) | (unsigned int)f2h(lo);
}

// ---------------------------------------------------------------------------
// K0 (merged, vectorized): weight swizzle blocks 0..276 (8 elems/thread,
// uint4 stores) + gather/cast blocks 277..532 (4 rows/block, packed stores).
//   frag layout: buf[((kt*NT+nt)*64+lane)*8+j] = W[kt*32+(lane>>4)*8+j][nt*16+(lane&15)]
// ---------------------------------------------------------------------------
__global__ void prep_all(const float* __restrict__ W1, const float* __restrict__ W2,
                         const float* __restrict__ ee, const int* __restrict__ eidx,
                         unsigned short* __restrict__ w1n,
                         unsigned short* __restrict__ w1s,
                         unsigned short* __restrict__ w2s,
                         unsigned short* __restrict__ emb) {
    const int N1n8 = 24 * 28 * 64;   // 43008  (uint4-granular counts)
    const int N1s8 = 24 * 14 * 64;   // 21504
    const int N28  = 7 * 14 * 64;    // 6272
    int bx = blockIdx.x;
    if (bx >= 277) {                  // gather + fp32->fp16, 4 rows/block
        int tid = threadIdx.x;
        int m = (bx - 277) * 4 + (tid >> 6);   // global row 0..1023
        int lane = tid & 63;
        int b = m >> 8, n = m & 255;
        int t = eidx[b * NN + n];
        const float* src = ee + ((size_t)b * TT + t) * DD;
        uint4* dst = (uint4*)(emb + ((size_t)b * NN + n) * DD);
        for (int chunk = lane; chunk < 96; chunk += 64) {
            const float4* s4 = (const float4*)(src + chunk * 8);
            float4 lo4 = s4[0], hi4 = s4[1];
            uint4 o;
            o.x = packh(lo4.x, lo4.y); o.y = packh(lo4.z, lo4.w);
            o.z = packh(hi4.x, hi4.y); o.w = packh(hi4.z, hi4.w);
            dst[chunk] = o;
        }
        return;
    }
    int idx8 = bx * 256 + threadIdx.x;
    if (idx8 < N1n8) {
        int lane = idx8 & 63, f = idx8 >> 6;
        int nt = f % 28, kt = f / 28;
        int k0 = kt * 32 + ((lane >> 4) << 3);     // base k, +j below
        int n = nt * 16 + (lane & 15);             // 0..447
        unsigned int o[4];
#pragma unroll
        for (int jp = 0; jp < 4; ++jp) {
            float v0, v1;
            int ka = k0 + 2 * jp, kb = ka + 1;
            if (n < HP) {
                v0 = (n < 200) ? W1[(size_t)ka * 200 + n] : 0.f;
                v1 = (n < 200) ? W1[(size_t)kb * 200 + n] : 0.f;
            } else {
                int c2 = n - HP;
                v0 = (c2 < 200) ? W1[(size_t)(768 + ka) * 200 + c2] : 0.f;
                v1 = (c2 < 200) ? W1[(size_t)(768 + kb) * 200 + c2] : 0.f;
            }
            o[jp] = packh(v0, v1);
        }
        *(uint4*)&w1n[(size_t)idx8 * 8] = make_uint4(o[0], o[1], o[2], o[3]);
    } else if (idx8 < N1n8 + N1s8) {
        int i2 = idx8 - N1n8;
        int lane = i2 & 63, f = i2 >> 6;
        int nt = f % NTILES, kt = f / NTILES;
        int k0 = kt * 32 + ((lane >> 4) << 3);
        int n = nt * 16 + (lane & 15);
        unsigned int o[4];
#pragma unroll
        for (int jp = 0; jp < 4; ++jp) {
            int ka = k0 + 2 * jp, kb = ka + 1;
            float v0 = (n < 200) ? W1[(size_t)(1536 + ka) * 200 + n] : 0.f;
            float v1 = (n < 200) ? W1[(size_t)(1536 + kb) * 200 + n] : 0.f;
            o[jp] = packh(v0, v1);
        }
        *(uint4*)&w1s[(size_t)i2 * 8] = make_uint4(o[0], o[1], o[2], o[3]);
    } else if (idx8 < N1n8 + N1s8 + N28) {
        int i2 = idx8 - N1n8 - N1s8;
        int lane = i2 & 63, f = i2 >> 6;
        int nt = f % NTILES, kt = f / NTILES;
        int k0 = kt * 32 + ((lane >> 4) << 3);
        int n = nt * 16 + (lane & 15);
        unsigned int o[4];
#pragma unroll
        for (int jp = 0; jp < 4; ++jp) {
            int ka = k0 + 2 * jp, kb = ka + 1;
            float v0 = (ka < 200 && n < 200) ? W2[(size_t)ka * 200 + n] : 0.f;
            float v1 = (kb < 200 && n < 200) ? W2[(size_t)kb * 200 + n] : 0.f;
            o[jp] = packh(v0, v1);
        }
        *(uint4*)&w2s[(size_t)i2 * 8] = make_uint4(o[0], o[1], o[2], o[3]);
    }
}

// ---------------------------------------------------------------------------
// K2: AB = emb(1024x768) @ [W1top|W1mid](768x448), fp16 MFMA, fp16 out.
//   256 one-wave blocks; register ping-pong prefetch.
// ---------------------------------------------------------------------------
__global__ __launch_bounds__(64)
void node_mfma(const unsigned short* __restrict__ emb,
               const unsigned short* __restrict__ w1n,
               unsigned short* __restrict__ AB) {
    int lane = threadIdx.x & 63;
    int q = lane >> 4, c = lane & 15;
    int mt = blockIdx.x >> 2;         // 0..63
    int ng = blockIdx.x & 3;          // 0..3
    int m0 = mt * 16;
    const uint4* ga = (const uint4*)emb + (size_t)(m0 + c) * 96;
    const uint4* gb = (const uint4*)w1n;

    f32x4 acc[7];
#pragma unroll
    for (int n = 0; n < 7; ++n) acc[n] = (f32x4){0.f, 0.f, 0.f, 0.f};

    uint4 aA, aB, bA[7], bB[7];
    aA = ga[q];
#pragma unroll
    for (int n = 0; n < 7; ++n) bA[n] = gb[((0 * 28 + ng * 7 + n) << 6) + lane];

#pragma unroll 1
    for (int kt = 0; kt < KT1; kt += 2) {
        aB = ga[(kt + 1) * 4 + q];
#pragma unroll
        for (int n = 0; n < 7; ++n) bB[n] = gb[(((kt + 1) * 28 + ng * 7 + n) << 6) + lane];
        {
            FragU a; a.u = aA;
#pragma unroll
            for (int n = 0; n < 7; ++n) {
                FragU bb; bb.u = bA[n];
                acc[n] = __builtin_amdgcn_mfma_f32_16x16x32_f16(a.h, bb.h, acc[n], 0, 0, 0);
            }
        }
        if (kt + 2 < KT1) {
            aA = ga[(kt + 2) * 4 + q];
#pragma unroll
            for (int n = 0; n < 7; ++n) bA[n] = gb[(((kt + 2) * 28 + ng * 7 + n) << 6) + lane];
        }
        {
            FragU a; a.u = aB;
#pragma unroll
            for (int n = 0; n < 7; ++n) {
                FragU bb; bb.u = bB[n];
                acc[n] = __builtin_amdgcn_mfma_f32_16x16x32_f16(a.h, bb.h, acc[n], 0, 0, 0);
            }
        }
    }
#pragma unroll
    for (int n = 0; n < 7; ++n) {
        int col = (ng * 7 + n) * 16 + c;
#pragma unroll
        for (int rr = 0; rr < 4; ++rr)
            AB[(size_t)(m0 + q * 4 + rr) * ABS + col] = f2h(acc[n][rr]);
    }
}

// ---------------------------------------------------------------------------
// K3: pair MLP (R15 geometry). Block = 128 threads = 2 waves (the nh pair)
//   for one (tile, 4-i-row group rp). acc[4][7] (28 MFMA per 7 weight loads),
//   ping-pong prefetch, setprio(1) around MFMA bursts (independent waves).
// ---------------------------------------------------------------------------
__global__ __launch_bounds__(128, 2)
void pair_wave(
    const unsigned short* __restrict__ emb,
    const unsigned short* __restrict__ w1s,
    const unsigned short* __restrict__ w2s,
    const unsigned short* __restrict__ AB,
    const float* __restrict__ b1, const float* __restrict__ b2,
    const float* __restrict__ W3, const float* __restrict__ b3,
    float* __restrict__ S) {
    int bid = blockIdx.x;
    int rp = bid / 544;               // 0..3 : 4-row group within tile
    int g = bid % 544;                // tile id; mates 544 apart (544%8==0)
    int b = g / TRI;
    int r = g % TRI;
    int ti = (int)((sqrtf(8.f * (float)r + 1.f) - 1.f) * 0.5f);
    while ((ti + 1) * (ti + 2) / 2 <= r) ++ti;
    while (ti * (ti + 1) / 2 > r) --ti;
    int tj = r - ti * (ti + 1) / 2;
    int i0 = ti << 4, j0 = tj << 4;

    int tid = threadIdx.x;
    int lane = tid & 63;
    int nh = tid >> 6;                // 0..1 (ntile half)
    int q = lane >> 4, c = lane & 15;
    int iA = i0 + rp * 4;             // rows iA..iA+3

    __shared__ __align__(16) unsigned short smH[4 * MTS];   // 28672 B (4 slots)
    __shared__ float sred[2][64];                           //   512 B

    const uint4* w1f = (const uint4*)w1s;
    const uint4* w2f = (const uint4*)w2s;
    const uint4* gI[4];
#pragma unroll
    for (int t = 0; t < 4; ++t)
        gI[t] = (const uint4*)(emb + ((size_t)b * NN + iA + t) * DD);
    const uint4* gJc = (const uint4*)(emb + ((size_t)b * NN + j0 + c) * DD);

    // ---- phase 1: acc[4][7] over K=768, ping-pong prefetch ----
    f32x4 acc[4][7];
#pragma unroll
    for (int t = 0; t < 4; ++t)
#pragma unroll
        for (int n = 0; n < 7; ++n)
            acc[t][n] = (f32x4){0.f, 0.f, 0.f, 0.f};

    {
        uint4 bfrA[7], bfrB[7];
        uint4 ejA, ejB, eA[4], eB[4];
#pragma unroll
        for (int n = 0; n < 7; ++n) bfrA[n] = w1f[(nh * 7 + n) * 64 + lane];
        ejA = gJc[q];
#pragma unroll
        for (int t = 0; t < 4; ++t) eA[t] = gI[t][q];

#pragma unroll 1
        for (int kt = 0; kt < KT1; kt += 2) {
            // prefetch kt+1 -> B
#pragma unroll
            for (int n = 0; n < 7; ++n)
                bfrB[n] = w1f[((kt + 1) * NTILES + nh * 7 + n) * 64 + lane];
            ejB = gJc[(kt + 1) * 4 + q];
#pragma unroll
            for (int t = 0; t < 4; ++t) eB[t] = gI[t][(kt + 1) * 4 + q];
            // compute kt (A)
            __builtin_amdgcn_s_setprio(1);
#pragma unroll
            for (int t = 0; t < 4; ++t) {
                FragU a;
                a.u.x = h2mul(eA[t].x, ejA.x); a.u.y = h2mul(eA[t].y, ejA.y);
                a.u.z = h2mul(eA[t].z, ejA.z); a.u.w = h2mul(eA[t].w, ejA.w);
#pragma unroll
                for (int n = 0; n < 7; ++n) {
                    FragU bb; bb.u = bfrA[n];
                    acc[t][n] = __builtin_amdgcn_mfma_f32_16x16x32_f16(a.h, bb.h, acc[t][n], 0, 0, 0);
                }
            }
            __builtin_amdgcn_s_setprio(0);
            // prefetch kt+2 -> A
            if (kt + 2 < KT1) {
#pragma unroll
                for (int n = 0; n < 7; ++n)
                    bfrA[n] = w1f[((kt + 2) * NTILES + nh * 7 + n) * 64 + lane];
                ejA = gJc[(kt + 2) * 4 + q];
#pragma unroll
                for (int t = 0; t < 4; ++t) eA[t] = gI[t][(kt + 2) * 4 + q];
            }
            // compute kt+1 (B)
            __builtin_amdgcn_s_setprio(1);
#pragma unroll
            for (int t = 0; t < 4; ++t) {
                FragU a;
                a.u.x = h2mul(eB[t].x, ejB.x); a.u.y = h2mul(eB[t].y, ejB.y);
                a.u.z = h2mul(eB[t].z, ejB.z); a.u.w = h2mul(eB[t].w, ejB.w);
#pragma unroll
                for (int n = 0; n < 7; ++n) {
                    FragU bb; bb.u = bfrB[n];
                    acc[t][n] = __builtin_amdgcn_mfma_f32_16x16x32_f16(a.h, bb.h, acc[t][n], 0, 0, 0);
                }
            }
            __builtin_amdgcn_s_setprio(0);
        }
    }

    // ---- epilogue: h1 = relu(acc + A[i] + Bv[j] + b1) -> smH (nh half) ----
    {
        unsigned int bvp[7][2];
#pragma unroll
        for (int n = 0; n < 7; ++n) {
            int h = ((nh * 7 + n) << 4) + c;
#pragma unroll
            for (int p = 0; p < 2; ++p) {
                unsigned int lo = AB[((size_t)b * NN + j0 + q * 4 + 2 * p) * ABS + HP + h];
                unsigned int hi = AB[((size_t)b * NN + j0 + q * 4 + 2 * p + 1) * ABS + HP + h];
                bvp[n][p] = (hi << 16) | lo;
            }
        }
#pragma unroll
        for (int t = 0; t < 4; ++t) {
            unsigned short* slot = &smH[t * MTS];
#pragma unroll
            for (int n = 0; n < 7; ++n) {
                int h = ((nh * 7 + n) << 4) + c;
                float b1v = (h < 200) ? b1[h] : 0.f;
                float af = h2f(AB[((size_t)b * NN + iA + t) * ABS + h]) + b1v;
                int kk2 = h >> 5, q2 = (h >> 3) & 3, j2 = h & 7;
                int fa = ((kk2 * 4 + q2) << 7) + j2;        // + jj*8 below
#pragma unroll
                for (int rr = 0; rr < 4; ++rr) {
                    float bvf = (rr & 1) ? hhi(bvp[n][rr >> 1]) : hlo(bvp[n][rr >> 1]);
                    slot[fa + ((q * 4 + rr) << 3)] =
                        f2h(fmaxf(acc[t][n][rr] + af + bvf, 0.f));
                }
            }
        }
    }
    __syncthreads();   // B1: both h-halves of all 4 slots in smH

    // ---- phase 2: acc2[4][7] over K=224, ping-pong weight prefetch ----
    f32x4 acc2[4][7];
#pragma unroll
    for (int t = 0; t < 4; ++t)
#pragma unroll
        for (int n = 0; n < 7; ++n)
            acc2[t][n] = (f32x4){0.f, 0.f, 0.f, 0.f};

    {
        uint4 bfrA[7], bfrB[7];
#pragma unroll
        for (int n = 0; n < 7; ++n) bfrA[n] = w2f[(nh * 7 + n) * 64 + lane];

#pragma unroll 1
        for (int kk = 0; kk < 6; kk += 2) {
#pragma unroll
            for (int n = 0; n < 7; ++n)
                bfrB[n] = w2f[((kk + 1) * NTILES + nh * 7 + n) * 64 + lane];
            __builtin_amdgcn_s_setprio(1);
#pragma unroll
            for (int t = 0; t < 4; ++t) {
                FragU a2;
                a2.u = *(const uint4*)(&smH[t * MTS + (((kk * 4 + q) * 16 + c) << 3)]);
#pragma unroll
                for (int n = 0; n < 7; ++n) {
                    FragU bb; bb.u = bfrA[n];
                    acc2[t][n] = __builtin_amdgcn_mfma_f32_16x16x32_f16(a2.h, bb.h, acc2[t][n], 0, 0, 0);
                }
            }
            __builtin_amdgcn_s_setprio(0);
#pragma unroll
            for (int n = 0; n < 7; ++n)
                bfrA[n] = w2f[((kk + 2) * NTILES + nh * 7 + n) * 64 + lane];
            __builtin_amdgcn_s_setprio(1);
#pragma unroll
            for (int t = 0; t < 4; ++t) {
                FragU a2;
                a2.u = *(const uint4*)(&smH[t * MTS + ((((kk + 1) * 4 + q) * 16 + c) << 3)]);
#pragma unroll
                for (int n = 0; n < 7; ++n) {
                    FragU bb; bb.u = bfrB[n];
                    acc2[t][n] = __builtin_amdgcn_mfma_f32_16x16x32_f16(a2.h, bb.h, acc2[t][n], 0, 0, 0);
                }
            }
            __builtin_amdgcn_s_setprio(0);
        }
        // tail kk=6 (already in bfrA)
        __builtin_amdgcn_s_setprio(1);
#pragma unroll
        for (int t = 0; t < 4; ++t) {
            FragU a2;
            a2.u = *(const uint4*)(&smH[t * MTS + (((6 * 4 + q) * 16 + c) << 3)]);
#pragma unroll
            for (int n = 0; n < 7; ++n) {
                FragU bb; bb.u = bfrA[n];
                acc2[t][n] = __builtin_amdgcn_mfma_f32_16x16x32_f16(a2.h, bb.h, acc2[t][n], 0, 0, 0);
            }
        }
        __builtin_amdgcn_s_setprio(0);
    }

    // ---- phase 3: partial dot relu(h2+b2).W3 over nh half -> sred ----
    {
        float b2v[7], w3v[7];
#pragma unroll
        for (int n = 0; n < 7; ++n) {
            int h = ((nh * 7 + n) << 4) + c;
            b2v[n] = (h < 200) ? b2[h] : 0.f;
            w3v[n] = (h < 200) ? W3[h] : 0.f;
        }
#pragma unroll
        for (int t = 0; t < 4; ++t) {
#pragma unroll
            for (int rr = 0; rr < 4; ++rr) {
                float part = 0.f;
#pragma unroll
                for (int n = 0; n < 7; ++n) {
                    float hv = fmaxf(acc2[t][n][rr] + b2v[n], 0.f);
                    part += hv * w3v[n];
                }
                part += __shfl_xor(part, 1);
                part += __shfl_xor(part, 2);
                part += __shfl_xor(part, 4);
                part += __shfl_xor(part, 8);
                if (c == 0)
                    sred[nh][t * 16 + q * 4 + rr] = part;
            }
        }
    }
    __syncthreads();   // B2: both partials in sred

    if (tid < 64) {
        int t = tid >> 4, jj = tid & 15;
        float s = sred[0][tid] + sred[1][tid] + b3[0];
        S[((size_t)b * NN + iA + t) * NN + j0 + jj] = s;
    }
}

// ---------------------------------------------------------------------------
// K4: masked softmax per row; diag logit = 0; invalid -> -1000
// ---------------------------------------------------------------------------
__global__ __launch_bounds__(256) void softmax_rows(const float* __restrict__ S,
                                                    float* __restrict__ out) {
    int b = blockIdx.x >> 8, i = blockIdx.x & 255;
    int j = threadIdx.x;
    int lane = j & 63, w = j >> 6;
    __shared__ float red[16];
    float x = (j < i) ? S[((size_t)b * NN + i) * NN + j] : ((j == i) ? 0.f : -1e30f);
    float m = x;
#pragma unroll
    for (int off = 32; off; off >>= 1) m = fmaxf(m, __shfl_xor(m, off));
    if (lane == 0) red[w] = m;
    __syncthreads();
    float mx = fmaxf(fmaxf(red[0], red[1]), fmaxf(red[2], red[3]));
    float e = (j <= i) ? __expf(x - mx) : 0.f;
    float s = e;
#pragma unroll
    for (int off = 32; off; off >>= 1) s += __shfl_xor(s, off);
    if (lane == 0) red[8 + w] = s;
    __syncthreads();
    float sum = red[8] + red[9] + red[10] + red[11];
    out[((size_t)b * NN + i) * NN + j] = (j <= i) ? (e / sum) : -1000.0f;
}

// ---------------------------------------------------------------------------
extern "C" void kernel_launch(void* const* d_in, const int* in_sizes, int n_in,
                              void* d_out, int out_size, void* d_ws, size_t ws_size,
                              hipStream_t stream) {
    const float* ee  = (const float*)d_in[0];
    const int*   eidx = (const int*)d_in[1];
    const float* W1  = (const float*)d_in[2];
    const float* b1  = (const float*)d_in[3];
    const float* W2  = (const float*)d_in[4];
    const float* b2  = (const float*)d_in[5];
    const float* W3  = (const float*)d_in[6];
    const float* b3  = (const float*)d_in[7];
    float* out = (float*)d_out;

    char* p = (char*)d_ws;
    unsigned short* emb = (unsigned short*)p; p += (size_t)NB * NN * DD * 2;       // 1.5 MB
    unsigned short* w1n = (unsigned short*)p; p += (size_t)24 * 28 * 512 * 2;      // 672 KB
    unsigned short* w1s = (unsigned short*)p; p += (size_t)24 * 14 * 512 * 2;      // 336 KB
    unsigned short* w2s = (unsigned short*)p; p += (size_t)7 * 14 * 512 * 2;       // 98 KB
    unsigned short* AB  = (unsigned short*)p; p += (size_t)NB * NN * ABS * 2;      // 896 KB
    float* S  = (float*)p; p += (size_t)NB * NN * NN * 4;                           // 1 MB

    prep_all<<<533, 256, 0, stream>>>(W1, W2, ee, eidx, w1n, w1s, w2s, emb);
    node_mfma<<<256, 64, 0, stream>>>(emb, w1n, AB);
    pair_wave<<<2176, 128, 0, stream>>>(emb, w1s, w2s, AB, b1, b2, W3, b3, S);
    softmax_rows<<<NB * NN, 256, 0, stream>>>(S, out);
}